// Round 6
// baseline (235.558 us; speedup 1.0000x reference)
//
#include <hip/hip_runtime.h>

// M[t, i*768+p, j*768+q] = A[t,i,j] * exp(-maha - 0.5*logdet(D_tij)), row-normalized.
// D is 2x2 SPD -> closed-form inverse, coef = A * det^-1/2.
// Structure: ONE WAVE PER OUTPUT ROW, PERSISTENT GRID-STRIDE.
// Lane covers 24 cols interleaved as col = k*256 + lane*4 (k=0..5) -> every
// float4 store is lane-contiguous (1KB/instr). Row sum = in-register
// __shfl_xor butterfly: zero LDS, zero barriers.
//
// R8 (resubmitted R10; two infra failures, never yet run): BREAK THE
// STORE->NEXT-ROW REGISTER DEPENDENCE. VMEM stores read their data VGPRs
// lazily after issue; overwriting them forces s_waitcnt vmcnt() first.
// Previous versions (95us kernel portion vs 36us write floor; nt stores,
// persistence, hoists all neutral) likely stalled every row start waiting
// for the previous row's 6 stores to reach L2 (~500cy of a ~900cy row).
// Changes:
//  - W_ROWS 4->2, row loop unrolled: fresh SSA locals per row, pressure ~110
//    VGPR -> allocator can ping-pong store buffers instead of reuse+wait.
//  - scale vals into a SEPARATE float4 o[6] before storing: earliest possible
//    register reuse is a full row's compute (~900cy) after store issue.
//  - RPB=8 -> 4608 slots, 768 blocks x 6 slots; 4 blocks/CU resident, no tail.

typedef unsigned int u32;

namespace {
constexpr float GAMMA_C   = 0.3f;
constexpr float JITTER_C  = 1e-5f;
constexpr float ELL_MIN_C = 0.05f;
constexpr float ELL_MAX_C = 10.0f;
constexpr int   NPT     = 768;
constexpr int   TSTEPS  = 24;
constexpr int   ROWS    = TSTEPS * 2 * NPT;   // 36864
constexpr int   W_ROWS  = 2;                  // rows per wave per slot
constexpr int   WAVES   = 4;                  // waves per block
constexpr int   THREADS = WAVES * 64;         // 256
constexpr int   RPB     = W_ROWS * WAVES;     // 8 rows per slot
constexpr int   SLOTS   = ROWS / RPB;         // 4608
constexpr int   BLOCKS  = 768;                // 6 slots per block exactly
}

__global__ __launch_bounds__(THREADS) void vlk_kernel(
    const float* __restrict__ S,         // [768,2]
    const float* __restrict__ mu_seq,    // [24,4]
    const float* __restrict__ Sg,        // [24,4,4]
    const float* __restrict__ A,         // [24,2,2]
    const float* __restrict__ rl,        // [2,2]
    float* __restrict__ out)             // [24,1536,1536]
{
    const int w    = threadIdx.x >> 6;
    const int lane = threadIdx.x & 63;

    // ---- S points for this lane's 12 q positions: invariant across slots ----
    float sx[12], sy[12];
#pragma unroll
    for (int m = 0; m < 3; ++m) {
        const int q0 = m * 256 + lane * 4;
        const float4 a4 = *((const float4*)(S + 2 * q0));      // x0 y0 x1 y1
        const float4 b4 = *((const float4*)(S + 2 * q0 + 4));  // x2 y2 x3 y3
        sx[4*m+0] = a4.x; sy[4*m+0] = a4.y;
        sx[4*m+1] = a4.z; sy[4*m+1] = a4.w;
        sx[4*m+2] = b4.x; sy[4*m+2] = b4.y;
        sx[4*m+3] = b4.z; sy[4*m+3] = b4.w;
    }

    const float g = GAMMA_C;

    for (int slot = blockIdx.x; slot < SLOTS; slot += BLOCKS) {
        const int base = slot * RPB;                // first row of this slot
        const int t    = base / (2 * NPT);
        const int rem  = base - t * (2 * NPT);
        const int i    = rem / NPT;                 // row-block index (uniform)
        const int p0   = rem - i * NPT + w * W_ROWS;

        // ---- per-(t,i) params for BOTH jj ----
        float mu[4];
#pragma unroll
        for (int k = 0; k < 4; ++k) mu[k] = mu_seq[t * 4 + k];
        float Sgm[4][4];
#pragma unroll
        for (int r = 0; r < 4; ++r)
#pragma unroll
            for (int c = 0; c < 4; ++c) Sgm[r][c] = Sg[t * 16 + r * 4 + c];

        float shift0[2], shift1[2], i00[2], i01x2[2], i11[2], coef[2];
        const int bi = 2 * i;
#pragma unroll
        for (int jj = 0; jj < 2; ++jj) {
            const int bj = 2 * jj;
            shift0[jj] = mu[bi]     - g * mu[bj];
            shift1[jj] = mu[bi + 1] - g * mu[bj + 1];
            const float b00 = Sgm[bi][bi]     - g*Sgm[bi][bj]     - g*Sgm[bj][bi]     + g*g*Sgm[bj][bj];
            const float b01 = Sgm[bi][bi+1]   - g*Sgm[bi][bj+1]   - g*Sgm[bj][bi+1]   + g*g*Sgm[bj][bj+1];
            const float b11 = Sgm[bi+1][bi+1] - g*Sgm[bi+1][bj+1] - g*Sgm[bj+1][bi+1] + g*g*Sgm[bj+1][bj+1];
            const float rlv = rl[i * 2 + jj];
            const float ell = ELL_MIN_C + (ELL_MAX_C - ELL_MIN_C) / (1.0f + __expf(-rlv));
            const float e2  = ell * ell + JITTER_C;
            const float D00 = e2 + 2.0f * b00;
            const float D01 =      2.0f * b01;
            const float D11 = e2 + 2.0f * b11;
            const float det  = D00 * D11 - D01 * D01;       // SPD -> det > 0
            const float rdet = 1.0f / det;
            i00[jj]   =  D11 * rdet;
            i01x2[jj] = -2.0f * D01 * rdet;                 // pre-doubled cross term
            i11[jj]   =  D00 * rdet;
            coef[jj] = A[(t * 2 + i) * 2 + jj] * rsqrtf(det);
        }

        // ---- 2 rows per wave, unrolled: fresh locals per row -> allocator can
        // ping-pong store buffers instead of reuse+vmcnt-stall ----
#pragma unroll
        for (int r = 0; r < W_ROWS; ++r) {
            const int p = p0 + r;
            const float sp0 = S[2 * p];          // uniform per wave -> broadcast
            const float sp1 = S[2 * p + 1];

            float cx[2], cy[2];
#pragma unroll
            for (int jj = 0; jj < 2; ++jj) {
                cx[jj] = sp0 - shift0[jj];
                cy[jj] = sp1 - shift1[jj];
            }

            float vals[24];
            float lsum = 0.0f;
#pragma unroll
            for (int k = 0; k < 6; ++k) {        // chunk: col = k*256 + lane*4
                const int jj = (k >= 3) ? 1 : 0;
                const int m  = k - 3 * jj;
                const float cx0 = cx[jj], cy0 = cy[jj];
                const float a0 = i00[jj], a1x2 = i01x2[jj], a2 = i11[jj], cf = coef[jj];
#pragma unroll
                for (int j = 0; j < 4; ++j) {
                    const float h0 = cx0 - sx[4*m+j];
                    const float h1 = cy0 - sy[4*m+j];
                    const float maha = (a0 * h0 + a1x2 * h1) * h0 + a2 * h1 * h1;
                    const float v = cf * __expf(-maha);
                    vals[4*k+j] = v;
                    lsum += v;
                }
            }

            // in-register wave reduction: all lanes end with the row total
#pragma unroll
            for (int off = 1; off < 64; off <<= 1) lsum += __shfl_xor(lsum, off, 64);
            const float inv = 1.0f / fmaxf(lsum, 1e-8f);    // clip(sum, 1e-8)

            // scale into a separate store buffer, then issue all 6 stores;
            // vals[] dies here, o[] is not reused until after the NEXT row's
            // full compute+reduce (~900cy) -> store latency hidden.
            float4 o[6];
#pragma unroll
            for (int k = 0; k < 6; ++k) {
                o[k].x = vals[4*k+0] * inv;
                o[k].y = vals[4*k+1] * inv;
                o[k].z = vals[4*k+2] * inv;
                o[k].w = vals[4*k+3] * inv;
            }
            float* op = out + (size_t)(base + w * W_ROWS + r) * (2 * NPT);
#pragma unroll
            for (int k = 0; k < 6; ++k) {
                *((float4*)(op + k * 256 + lane * 4)) = o[k];
            }
        }
    }
}

extern "C" void kernel_launch(void* const* d_in, const int* in_sizes, int n_in,
                              void* d_out, int out_size, void* d_ws, size_t ws_size,
                              hipStream_t stream) {
    vlk_kernel<<<BLOCKS, THREADS, 0, stream>>>(
        (const float*)d_in[0],   // S
        (const float*)d_in[1],   // mu_seq
        (const float*)d_in[2],   // Sigma_seq
        (const float*)d_in[3],   // A_seq
        (const float*)d_in[4],   // raw_ell
        (float*)d_out);
}